// Round 4
// baseline (298.194 us; speedup 1.0000x reference)
//
#include <hip/hip_runtime.h>
#include <math.h>

#define IN_DIM   256
#define OUT_DIM  128
#define NCOEF    19          // NUM + K
#define BATCH    2048
#define BT       4           // batches per block
#define TILE_F   (IN_DIM * NCOEF)   // 4864 floats per o-tile

__device__ __forceinline__ float softplus_f(float v) {
  return (v > 20.0f) ? v : log1pf(expf(v));
}

// ---------------- prep: transform coef (monotonic rows), fold scales, transpose ----
__global__ void kan_prep(const float* __restrict__ coef,
                         const float* __restrict__ ssp,
                         const float* __restrict__ sbase,
                         const float* __restrict__ mask,
                         const float* __restrict__ bmask,
                         float* __restrict__ coefT,   // [o][i][19]
                         float* __restrict__ At,      // [o][i]
                         float* __restrict__ Bt) {    // [o][i]
  int g = blockIdx.x * 256 + threadIdx.x;   // g = o*256 + i
  int o = g >> 8;
  int i = g & 255;
  const float* src = coef + ((size_t)i * OUT_DIM + o) * NCOEF;
  float c[NCOEF];
#pragma unroll
  for (int d = 0; d < NCOEF; ++d) c[d] = src[d];
  if (i < 2) {
    // MONO = ((0,+1),(1,-1)): cumsum(softplus) with direction
    float dir = (i == 0) ? 1.0f : -1.0f;
    float acc = 0.0f;
#pragma unroll
    for (int d = 0; d < NCOEF; ++d) { acc += softplus_f(c[d]); c[d] = dir * acc; }
  }
  float* dst = coefT + (size_t)g * NCOEF;
#pragma unroll
  for (int d = 0; d < NCOEF; ++d) dst[d] = c[d];
  int io = i * OUT_DIM + o;
  float m = mask[io];
  At[g] = m * softplus_f(ssp[io]);
  Bt[g] = m * bmask[io] * sbase[io];
}

// ---------------- wave64 sum via DPP (pure VALU), result in lane 63 ----------------
__device__ __forceinline__ float wave_reduce(float v) {
  int t;
  t = __builtin_amdgcn_update_dpp(0, __float_as_int(v), 0x111, 0xf, 0xf, true); v += __int_as_float(t); // row_shr:1
  t = __builtin_amdgcn_update_dpp(0, __float_as_int(v), 0x112, 0xf, 0xf, true); v += __int_as_float(t); // row_shr:2
  t = __builtin_amdgcn_update_dpp(0, __float_as_int(v), 0x114, 0xf, 0xf, true); v += __int_as_float(t); // row_shr:4
  t = __builtin_amdgcn_update_dpp(0, __float_as_int(v), 0x118, 0xf, 0xf, true); v += __int_as_float(t); // row_shr:8
  t = __builtin_amdgcn_update_dpp(0, __float_as_int(v), 0x142, 0xa, 0xf, true); v += __int_as_float(t); // row_bcast:15 -> rows 1,3
  t = __builtin_amdgcn_update_dpp(0, __float_as_int(v), 0x143, 0xc, 0xf, true); v += __int_as_float(t); // row_bcast:31 -> rows 2,3
  return v;
}

// ---------------- main: no LDS staging, no per-iter barriers ----------------
__global__ __launch_bounds__(512, 4) void kan_main(
    const float* __restrict__ x,
    const float* __restrict__ coefT,
    const float* __restrict__ At,
    const float* __restrict__ Bt,
    float* __restrict__ out,
    float* __restrict__ preacts,
    float* __restrict__ postacts,
    float* __restrict__ postspline) {
  __shared__ float s_out[BT][OUT_DIM][4];             // 8 KB only

  const int tid  = threadIdx.x;
  const int i    = tid & 255;
  const int bsub = tid >> 8;        // 0..1 -> handles b_local {2*bsub, 2*bsub+1}
  const int wq   = (tid >> 6) & 3;  // wave index within i-group
  const int b0   = blockIdx.x * BT;

  float xv[2], sl[2], wv[2][4];
  int   wi[2][4];

#pragma unroll
  for (int bb = 0; bb < 2; ++bb) {
    int b = b0 + bsub * 2 + bb;
    float xx = x[(size_t)b * IN_DIM + i];
    xv[bb] = xx;
    sl[bb] = xx / (1.0f + expf(-xx));          // silu

    // locate interval: knots g(a) = -1.375 + 0.125*a  (bit-exact vs reference grid)
    float tpos = (xx + 1.375f) * 8.0f;
    int j = (int)floorf(tpos);
    bool valid = (j >= 0) && (j <= 21);
    int jc = valid ? j : 3;

    // local Cox-de Boor: N[m] = B_{jc-p+m, p}(x)
    float N[4] = {1.0f, 0.0f, 0.0f, 0.0f};
#pragma unroll
    for (int p = 1; p <= 3; ++p) {
      const float inv = (p == 1) ? 8.0f : ((p == 2) ? 4.0f : (8.0f / 3.0f));
      float Np[4] = {0.0f, 0.0f, 0.0f, 0.0f};
#pragma unroll
      for (int m = 0; m < 4; ++m) {
        if (m <= p) {
          float ga = -1.375f + 0.125f * (float)(jc + m - p);
          float v = 0.0f;
          if (m > 0) v += (xx - ga) * inv * N[m - 1];
          if (m < p) v += ((ga + 0.125f * (float)(p + 1)) - xx) * inv * N[m];
          Np[m] = v;
        }
      }
#pragma unroll
      for (int m = 0; m < 4; ++m) N[m] = Np[m];
    }
#pragma unroll
    for (int r = 0; r < 4; ++r) {
      int dr = jc - 3 + r;
      bool ok = valid && (dr >= 0) && (dr <= 18);
      wv[bb][r] = ok ? N[r] : 0.0f;
      wi[bb][r] = i * NCOEF + (ok ? dr : 0);
    }
  }

  size_t off0 = ((size_t)(b0 + bsub * 2)     * OUT_DIM) * IN_DIM + i;
  size_t off1 = ((size_t)(b0 + bsub * 2 + 1) * OUT_DIM) * IN_DIM + i;

  // ---- register double-buffer: gather 4 coef/lane/bb straight from L2
  float cA[2][4], cB[2][4];
  float aA, bA, aB, bB;
#pragma unroll
  for (int bb = 0; bb < 2; ++bb)
#pragma unroll
    for (int r = 0; r < 4; ++r) cA[bb][r] = coefT[wi[bb][r]];    // o = 0
  aA = At[i];
  bA = Bt[i];

#define KAN_BODY(o_, C_, A_, B_)                                          \
  do {                                                                    \
    _Pragma("unroll")                                                     \
    for (int bb = 0; bb < 2; ++bb) {                                      \
      int bl = bsub * 2 + bb;                                             \
      float sp = wv[bb][0] * C_[bb][0] + wv[bb][1] * C_[bb][1]            \
               + wv[bb][2] * C_[bb][2] + wv[bb][3] * C_[bb][3];           \
      float ya = A_ * sp + B_ * sl[bb];                                   \
      size_t off = (bb == 0 ? off0 : off1) + (size_t)(o_) * IN_DIM;       \
      __builtin_nontemporal_store(sp,     postspline + off);              \
      __builtin_nontemporal_store(ya,     postacts   + off);              \
      __builtin_nontemporal_store(xv[bb], preacts    + off);              \
      float red = wave_reduce(ya);                                        \
      if ((tid & 63) == 63) s_out[bl][o_][wq] = red;                      \
    }                                                                     \
  } while (0)

  for (int oo = 0; oo < OUT_DIM; oo += 2) {
    {  // o = oo: consume A, prefetch oo+1 -> B
      const int on = oo + 1;                       // always < OUT_DIM
      const float* cpn = coefT + (size_t)on * TILE_F;
#pragma unroll
      for (int bb = 0; bb < 2; ++bb)
#pragma unroll
        for (int r = 0; r < 4; ++r) cB[bb][r] = cpn[wi[bb][r]];
      aB = At[on * IN_DIM + i];
      bB = Bt[on * IN_DIM + i];
      KAN_BODY(oo, cA, aA, bA);
    }
    {  // o = oo+1: consume B, prefetch oo+2 -> A (clamped at the end)
      const int on = (oo + 2 < OUT_DIM) ? oo + 2 : OUT_DIM - 1;
      const float* cpn = coefT + (size_t)on * TILE_F;
#pragma unroll
      for (int bb = 0; bb < 2; ++bb)
#pragma unroll
        for (int r = 0; r < 4; ++r) cA[bb][r] = cpn[wi[bb][r]];
      aA = At[on * IN_DIM + i];
      bA = Bt[on * IN_DIM + i];
      KAN_BODY(oo + 1, cB, aB, bB);
    }
  }
#undef KAN_BODY

  __syncthreads();   // single block-wide barrier: s_out ready
  {
    int bl = tid >> 7;       // 0..3
    int o  = tid & 127;
    float s = s_out[bl][o][0] + s_out[bl][o][1] + s_out[bl][o][2] + s_out[bl][o][3];
    out[(size_t)(b0 + bl) * OUT_DIM + o] = s;
  }
}

extern "C" void kernel_launch(void* const* d_in, const int* in_sizes, int n_in,
                              void* d_out, int out_size, void* d_ws, size_t ws_size,
                              hipStream_t stream) {
  (void)in_sizes; (void)n_in; (void)out_size; (void)ws_size;

  const float* x     = (const float*)d_in[0];
  const float* coef  = (const float*)d_in[1];
  const float* ssp   = (const float*)d_in[2];
  const float* sbase = (const float*)d_in[3];
  // d_in[4] = grid (analytic knots are bit-identical; unused)
  const float* mask  = (const float*)d_in[5];
  const float* bmask = (const float*)d_in[6];

  float* coefT = (float*)d_ws;                                   // 622592 f
  float* At    = coefT + (size_t)OUT_DIM * IN_DIM * NCOEF;       // 32768 f
  float* Bt    = At + (size_t)OUT_DIM * IN_DIM;                  // 32768 f

  float* out        = (float*)d_out;
  float* preacts    = out + (size_t)BATCH * OUT_DIM;
  float* postacts   = preacts + (size_t)BATCH * OUT_DIM * IN_DIM;
  float* postspline = postacts + (size_t)BATCH * OUT_DIM * IN_DIM;

  kan_prep<<<(OUT_DIM * IN_DIM) / 256, 256, 0, stream>>>(coef, ssp, sbase, mask, bmask,
                                                         coefT, At, Bt);
  kan_main<<<BATCH / BT, 512, 0, stream>>>(x, coefT, At, Bt,
                                           out, preacts, postacts, postspline);
}

// Round 5
// 187.491 us; speedup vs baseline: 1.5904x; 1.5904x over previous
//
#include <hip/hip_runtime.h>
#include <math.h>

#define IN_DIM   256
#define OUT_DIM  128
#define NCOEF    19          // NUM + K
#define BATCH    2048
#define BT       4           // batches per block
#define TILE_F   (IN_DIM * NCOEF)   // 4864 floats per o-tile
#define WROWS    32                 // coef rows owned by one wave
#define WFLOATS  (WROWS * NCOEF)    // 608 floats per wave-slice

__device__ __forceinline__ float softplus_f(float v) {
  return (v > 20.0f) ? v : log1pf(expf(v));
}

// async global->LDS, 16B per lane (linear, lane-ordered dest)
__device__ __forceinline__ void load_lds16(const float* g, float* l) {
  __builtin_amdgcn_global_load_lds(
      (const __attribute__((address_space(1))) void*)g,
      (__attribute__((address_space(3))) void*)l,
      16, 0, 0);
}

// stage one wave-slice (608 floats) into wave-private LDS
__device__ __forceinline__ void stage_wave(const float* src, float* dst, int lane) {
  load_lds16(src + lane * 4,       dst + lane * 4);
  load_lds16(src + 256 + lane * 4, dst + 256 + lane * 4);
  if (lane < 24) load_lds16(src + 512 + lane * 4, dst + 512 + lane * 4);
}

// ---------------- prep: transform coef (monotonic rows), fold scales, transpose ----
__global__ void kan_prep(const float* __restrict__ coef,
                         const float* __restrict__ ssp,
                         const float* __restrict__ sbase,
                         const float* __restrict__ mask,
                         const float* __restrict__ bmask,
                         float* __restrict__ coefT,   // [o][i][19]
                         float* __restrict__ At,      // [o][i]
                         float* __restrict__ Bt) {    // [o][i]
  int g = blockIdx.x * 256 + threadIdx.x;   // g = o*256 + i
  int o = g >> 8;
  int i = g & 255;
  const float* src = coef + ((size_t)i * OUT_DIM + o) * NCOEF;
  float c[NCOEF];
#pragma unroll
  for (int d = 0; d < NCOEF; ++d) c[d] = src[d];
  if (i < 2) {
    // MONO = ((0,+1),(1,-1)): cumsum(softplus) with direction
    float dir = (i == 0) ? 1.0f : -1.0f;
    float acc = 0.0f;
#pragma unroll
    for (int d = 0; d < NCOEF; ++d) { acc += softplus_f(c[d]); c[d] = dir * acc; }
  }
  float* dst = coefT + (size_t)g * NCOEF;
#pragma unroll
  for (int d = 0; d < NCOEF; ++d) dst[d] = c[d];
  int io = i * OUT_DIM + o;
  float m = mask[io];
  At[g] = m * softplus_f(ssp[io]);
  Bt[g] = m * bmask[io] * sbase[io];
}

// ---- 32-lane DPP sum: lane31 = sum(lanes 0..31), lane63 = sum(lanes 32..63)
__device__ __forceinline__ float half_reduce(float v) {
  int t;
  t = __builtin_amdgcn_update_dpp(0, __float_as_int(v), 0x111, 0xf, 0xf, true); v += __int_as_float(t); // row_shr:1
  t = __builtin_amdgcn_update_dpp(0, __float_as_int(v), 0x112, 0xf, 0xf, true); v += __int_as_float(t); // row_shr:2
  t = __builtin_amdgcn_update_dpp(0, __float_as_int(v), 0x114, 0xf, 0xf, true); v += __int_as_float(t); // row_shr:4
  t = __builtin_amdgcn_update_dpp(0, __float_as_int(v), 0x118, 0xf, 0xf, true); v += __int_as_float(t); // row_shr:8
  t = __builtin_amdgcn_update_dpp(0, __float_as_int(v), 0x142, 0xa, 0xf, true); v += __int_as_float(t); // row_bcast:15 -> rows 1,3
  return v;
}

// ---------------- main: wave-autonomous, NO block barriers in the o-loop ----------
__global__ __launch_bounds__(512, 4) void kan_main(
    const float* __restrict__ x,
    const float* __restrict__ coefT,
    const float* __restrict__ At,
    const float* __restrict__ Bt,
    float* __restrict__ out,
    float* __restrict__ preacts,
    float* __restrict__ postacts,
    float* __restrict__ postspline) {
  __shared__ __align__(16) float s_coef[8][2][WFLOATS];  // 8 waves x dbuf x 2432 B
  __shared__ float s_out[BT][OUT_DIM][8];                // 16 KB

  const int tid  = threadIdx.x;
  const int w    = tid >> 6;          // wave 0..7
  const int lane = tid & 63;
  const int il   = lane & 31;         // local coef row
  const int bsub = lane >> 5;         // 0..1
  const int i    = w * WROWS + il;    // global input dim 0..255
  const int b0   = blockIdx.x * BT;

  float xv[2], sl[2], wv[2][4];
  int   wl[2][4];                     // LDS-local gather indices (il*19 + tap)

#pragma unroll
  for (int bb = 0; bb < 2; ++bb) {
    int b = b0 + 2 * bsub + bb;
    float xx = x[(size_t)b * IN_DIM + i];
    xv[bb] = xx;
    sl[bb] = xx / (1.0f + expf(-xx));          // silu

    // locate interval: knots g(a) = -1.375 + 0.125*a  (bit-exact vs reference grid)
    float tpos = (xx + 1.375f) * 8.0f;
    int j = (int)floorf(tpos);
    bool valid = (j >= 0) && (j <= 21);
    int jc = valid ? j : 3;

    // local Cox-de Boor: N[m] = B_{jc-p+m, p}(x)
    float N[4] = {1.0f, 0.0f, 0.0f, 0.0f};
#pragma unroll
    for (int p = 1; p <= 3; ++p) {
      const float inv = (p == 1) ? 8.0f : ((p == 2) ? 4.0f : (8.0f / 3.0f));
      float Np[4] = {0.0f, 0.0f, 0.0f, 0.0f};
#pragma unroll
      for (int m = 0; m < 4; ++m) {
        if (m <= p) {
          float ga = -1.375f + 0.125f * (float)(jc + m - p);
          float v = 0.0f;
          if (m > 0) v += (xx - ga) * inv * N[m - 1];
          if (m < p) v += ((ga + 0.125f * (float)(p + 1)) - xx) * inv * N[m];
          Np[m] = v;
        }
      }
#pragma unroll
      for (int m = 0; m < 4; ++m) N[m] = Np[m];
    }
#pragma unroll
    for (int r = 0; r < 4; ++r) {
      int dr = jc - 3 + r;
      bool ok = valid && (dr >= 0) && (dr <= 18);
      wv[bb][r] = ok ? N[r] : 0.0f;
      wl[bb][r] = il * NCOEF + (ok ? dr : 0);
    }
  }

  const size_t woff = (size_t)w * WFLOATS;   // this wave's slice within an o-tile
  size_t off0 = ((size_t)(b0 + 2 * bsub)     * OUT_DIM) * IN_DIM + i;
  size_t off1 = ((size_t)(b0 + 2 * bsub + 1) * OUT_DIM) * IN_DIM + i;

  // ---- prologue (wave-private): stage o=0 into buf0, prefetch scales
  stage_wave(coefT + woff, &s_coef[w][0][0], lane);
  float aC = At[i];
  float bC = Bt[i];
  asm volatile("s_waitcnt vmcnt(0)" ::: "memory");   // wave-level: slice landed

#define KAN_BODY(o_, SC_, A_, B_)                                         \
  do {                                                                    \
    _Pragma("unroll")                                                     \
    for (int bb = 0; bb < 2; ++bb) {                                      \
      float sp = wv[bb][0] * SC_[wl[bb][0]] + wv[bb][1] * SC_[wl[bb][1]]  \
               + wv[bb][2] * SC_[wl[bb][2]] + wv[bb][3] * SC_[wl[bb][3]]; \
      float ya = A_ * sp + B_ * sl[bb];                                   \
      size_t off = (bb == 0 ? off0 : off1) + (size_t)(o_) * IN_DIM;       \
      __builtin_nontemporal_store(sp,     postspline + off);              \
      __builtin_nontemporal_store(ya,     postacts   + off);              \
      __builtin_nontemporal_store(xv[bb], preacts    + off);              \
      float red = half_reduce(ya);                                        \
      if (il == 31) s_out[2 * bsub + bb][o_][w] = red;                    \
    }                                                                     \
  } while (0)

  for (int oo = 0; oo < OUT_DIM; oo += 2) {
    {  // o = oo: consume buf0, prefetch oo+1 -> buf1
      const int on = oo + 1;                       // always < OUT_DIM
      stage_wave(coefT + (size_t)on * TILE_F + woff, &s_coef[w][1][0], lane);
      float aN = At[on * IN_DIM + i];
      float bN = Bt[on * IN_DIM + i];
      asm volatile("" ::: "memory");               // pin loads before stores in FIFO
      const float* sc = &s_coef[w][0][0];
      KAN_BODY(oo, sc, aC, bC);
      // drain: [stores oo-1][stage+scale loads][stores oo] -> leave 6 stores in flight
      asm volatile("s_waitcnt vmcnt(6)" ::: "memory");
      aC = aN; bC = bN;
    }
    {  // o = oo+1: consume buf1, prefetch oo+2 -> buf0 (clamped; keeps count uniform)
      const int on = (oo + 2 < OUT_DIM) ? oo + 2 : OUT_DIM - 1;
      stage_wave(coefT + (size_t)on * TILE_F + woff, &s_coef[w][0][0], lane);
      float aN = At[on * IN_DIM + i];
      float bN = Bt[on * IN_DIM + i];
      asm volatile("" ::: "memory");
      const float* sc = &s_coef[w][1][0];
      KAN_BODY(oo + 1, sc, aC, bC);
      asm volatile("s_waitcnt vmcnt(6)" ::: "memory");
      aC = aN; bC = bN;
    }
  }
#undef KAN_BODY

  __syncthreads();   // single block-wide barrier: s_out ready
  {
    int bl = tid >> 7;       // 0..3
    int o  = tid & 127;
    const float* p = &s_out[bl][o][0];
    float s = ((p[0] + p[1]) + (p[2] + p[3])) + ((p[4] + p[5]) + (p[6] + p[7]));
    out[(size_t)(b0 + bl) * OUT_DIM + o] = s;
  }
}

extern "C" void kernel_launch(void* const* d_in, const int* in_sizes, int n_in,
                              void* d_out, int out_size, void* d_ws, size_t ws_size,
                              hipStream_t stream) {
  (void)in_sizes; (void)n_in; (void)out_size; (void)ws_size;

  const float* x     = (const float*)d_in[0];
  const float* coef  = (const float*)d_in[1];
  const float* ssp   = (const float*)d_in[2];
  const float* sbase = (const float*)d_in[3];
  // d_in[4] = grid (analytic knots are bit-identical; unused)
  const float* mask  = (const float*)d_in[5];
  const float* bmask = (const float*)d_in[6];

  float* coefT = (float*)d_ws;                                   // 622592 f
  float* At    = coefT + (size_t)OUT_DIM * IN_DIM * NCOEF;       // 32768 f
  float* Bt    = At + (size_t)OUT_DIM * IN_DIM;                  // 32768 f

  float* out        = (float*)d_out;
  float* preacts    = out + (size_t)BATCH * OUT_DIM;
  float* postacts   = preacts + (size_t)BATCH * OUT_DIM * IN_DIM;
  float* postspline = postacts + (size_t)BATCH * OUT_DIM * IN_DIM;

  kan_prep<<<(OUT_DIM * IN_DIM) / 256, 256, 0, stream>>>(coef, ssp, sbase, mask, bmask,
                                                         coefT, At, Bt);
  kan_main<<<BATCH / BT, 512, 0, stream>>>(x, coefT, At, Bt,
                                           out, preacts, postacts, postspline);
}